// Round 3
// baseline (161.762 us; speedup 1.0000x reference)
//
#include <hip/hip_runtime.h>
#include <hip/hip_bf16.h>
#include <math.h>

// CrossEntropy3d OHEM: predict (n=2, c=12, d=64, h=128, w=128) f32,
// target (2,64,128,128) int32. Class stride = d*h*w = 1<<20 floats (4 MB).
//
// R12: global_load_lds DMA staging experiment.
// Evidence trail: main_pass is ~90% exposed memory latency (~2 TB/s
// effective, VALUBusy 5-10%, LLC-resident replay same dur => not BW-bound).
// Every prior attempt (2x waves R5, nt R6, VGPR->LDS staging R7, wide live
// loads R8, stream dwell R9) kept loads on the VGPR-return path. This is
// the untried hardware path: fire-and-forget global->LDS DMA, no VGPR
// destination, 24 x 1KB legally in flight per wave at zero register cost.
// Structure: block = 2048 contiguous px; 2 phases x 6 classes (48 KB LDS,
// class-major px-linear -> satisfies wave-uniform-base + lane*16 dest
// constraint, m104); 3 blocks/CU so cross-block TLP overlaps compute with
// other blocks' DMA. ds_read_b128 at 16B lane stride = conflict-free.
// Hot math / epilogue / reduce / fallback unchanged from the 156.7us R11.
// R10 lesson kept: dispatch boundary IS the producer->consumer release;
// no per-block fences/atomics in the hot path.
// Fixed harness overhead in timed window: ws poison ~59us + d_in restore
// ~33us => ~95us floor.

#define IGNORE_LABEL 255
#define MIN_KEPT 10000u

constexpr int   C         = 12;
constexpr int   PIX_SHIFT = 20;              // d*h*w = 1<<20
constexpr int   PIX_MASK  = (1 << PIX_SHIFT) - 1;
constexpr int   NBINS     = 2048;            // histogram over (0.9, 1.0]
constexpr float BIN_SCALE = (float)NBINS / 0.1f;

struct Ws {
    double       sum_p3;     // fallback sum (atomics; rare path only)
    unsigned int cnt_p3;
    unsigned int flag;       // 1 => fallback must run
    float        threshold;  // fallback threshold
    unsigned int done;       // main-pass arrival counter (unused here)
    unsigned int done2;      // fallback arrival counter
    unsigned int pad[9];     // pad to 64 B
    unsigned int hist[NBINS];
};
// uint4 per main block (sle, sva as float bits; cle, cva) right after Ws.

__device__ inline float wave_reduce_f(float v) {
    #pragma unroll
    for (int o = 32; o > 0; o >>= 1) v += __shfl_down(v, o, 64);
    return v;
}
__device__ inline unsigned int wave_reduce_u(unsigned int v) {
    #pragma unroll
    for (int o = 32; o > 0; o >>= 1) v += __shfl_down(v, o, 64);
    return v;
}
__device__ inline double wave_reduce_d(double v) {
    #pragma unroll
    for (int o = 32; o > 0; o >>= 1) v += __shfl_down(v, o, 64);
    return v;
}

// 16B-per-lane global->LDS DMA. LDS dest = l + lane*16 (wave-uniform base);
// global src is per-lane. Size must be a literal (guide §5).
__device__ inline void stage16(const float* g, float* l) {
    __builtin_amdgcn_global_load_lds(
        (const __attribute__((address_space(1))) void*)g,
        (__attribute__((address_space(3))) void*)l,
        16, 0, 0);
}

__global__ __launch_bounds__(256, 3) void main_pass_kernel(
        const float* __restrict__ pred, const int* __restrict__ tgt,
        Ws* __restrict__ ws, uint4* __restrict__ partials, int npix) {
    __shared__ float smem[6 * 2048];          // 48 KB: 6 classes x 2048 px

    const int blk   = blockIdx.x;
    const int t     = threadIdx.x;
    const int wave  = t >> 6, lane = t & 63;
    const int bpix0 = blk << 11;              // 2048 px per block
    if (bpix0 >= npix) return;

    // pred base for class 0 of this block's sample (blocks never straddle
    // the sample boundary: 2048 | 1<<20)
    const size_t sbase = (((size_t)(bpix0 >> PIX_SHIFT) * C) << PIX_SHIFT)
                       + (size_t)(bpix0 & PIX_MASK);

    // labels: thread t owns px {t*4..t*4+3} and {1024+t*4..+3} (block-local)
    const int4 la = *(const int4*)(tgt + bpix0 + (t << 2));
    const int4 lb = *(const int4*)(tgt + bpix0 + 1024 + (t << 2));
    const int lab[8] = {la.x, la.y, la.z, la.w, lb.x, lb.y, lb.z, lb.w};

    float E[8]  = {0,0,0,0,0,0,0,0};
    float ll[8] = {0,0,0,0,0,0,0,0};

    // per-wave staging source: wave w covers px [w*512, w*512+512) per class
    const float* gw = pred + sbase + (wave << 9) + (lane << 2);

    #pragma unroll
    for (int ph = 0; ph < 2; ++ph) {
        // ---- stage 6 classes (12 x 1KB DMA per wave, all in flight) ----
        #pragma unroll
        for (int ci = 0; ci < 6; ++ci) {
            const int c = ph * 6 + ci;
            const float* g0 = gw + ((size_t)c << PIX_SHIFT);
            float* l0 = smem + (ci << 11) + (wave << 9);   // wave-uniform
            stage16(g0,       l0);         // px [w*512     , +256)
            stage16(g0 + 256, l0 + 256);   // px [w*512+256 , +512)
        }
        __syncthreads();   // vmcnt drain + barrier: all 6 classes landed

        // ---- compute from LDS (ds_read_b128, 16B lane stride, 0-conflict)
        #pragma unroll
        for (int ci = 0; ci < 6; ++ci) {
            const int c = ph * 6 + ci;
            const float4 v0 = *(const float4*)(smem + (ci << 11) + (t << 2));
            const float4 v1 = *(const float4*)(smem + (ci << 11) + 1024 + (t << 2));
            const float vv[8] = {v0.x, v0.y, v0.z, v0.w, v1.x, v1.y, v1.z, v1.w};
            #pragma unroll
            for (int j = 0; j < 8; ++j) {
                E[j] += __expf(vv[j]);
                if (lab[j] == c) ll[j] = vv[j];
            }
        }
        __syncthreads();   // reads done before next phase restages buffer
    }

    float        my_sle = 0.0f, my_sva = 0.0f;
    unsigned int my_cle = 0u,   my_cva = 0u;
    #pragma unroll
    for (int j = 0; j < 8; ++j) {
        const float ls   = __logf(E[j]);
        const float nll  = ls - ll[j];
        const float prob = __expf(ll[j] - ls);
        if (lab[j] != IGNORE_LABEL) {
            my_cva += 1u;
            my_sva += nll;
            if (prob <= 0.9f) {
                my_cle += 1u;
                my_sle += nll;
            } else {
                int b = (int)((prob - 0.9f) * BIN_SCALE);
                b = b < 0 ? 0 : (b >= NBINS - 1 ? NBINS - 1 : b);
                atomicAdd(&ws->hist[b], 1u);   // rare
            }
        }
    }

    __shared__ float        s_le[4], s_va[4];
    __shared__ unsigned int s_cle[4], s_cva[4];
    const float        r_le = wave_reduce_f(my_sle);
    const float        r_va = wave_reduce_f(my_sva);
    const unsigned int r_cl = wave_reduce_u(my_cle);
    const unsigned int r_cv = wave_reduce_u(my_cva);
    if (lane == 0) { s_le[wave] = r_le; s_va[wave] = r_va; s_cle[wave] = r_cl; s_cva[wave] = r_cv; }
    __syncthreads();
    if (t == 0) {
        uint4 p;
        p.x = __float_as_uint(s_le[0] + s_le[1] + s_le[2] + s_le[3]);
        p.y = __float_as_uint(s_va[0] + s_va[1] + s_va[2] + s_va[3]);
        p.z = s_cle[0] + s_cle[1] + s_cle[2] + s_cle[3];
        p.w = s_cva[0] + s_cva[1] + s_cva[2] + s_cva[3];
        partials[blk] = p;   // fire-and-forget, distinct lines
    }
}

__global__ __launch_bounds__(1024) void reduce_finalize_kernel(
        Ws* __restrict__ ws, const uint4* __restrict__ partials,
        int nblocks, float* __restrict__ out) {
    double       sle = 0.0, sva = 0.0;
    unsigned int cle = 0u,  cva = 0u;
    for (int i = threadIdx.x; i < nblocks; i += 1024) {
        const uint4 p = partials[i];
        sle += (double)__uint_as_float(p.x);
        sva += (double)__uint_as_float(p.y);
        cle += p.z;
        cva += p.w;
    }
    __shared__ double       d_le[16], d_va[16];
    __shared__ unsigned int u_le[16], u_va[16];
    const int wid = threadIdx.x >> 6, lane = threadIdx.x & 63;
    const double       r_sle = wave_reduce_d(sle);
    const double       r_sva = wave_reduce_d(sva);
    const unsigned int r_cle = wave_reduce_u(cle);
    const unsigned int r_cva = wave_reduce_u(cva);
    if (lane == 0) { d_le[wid] = r_sle; d_va[wid] = r_sva; u_le[wid] = r_cle; u_va[wid] = r_cva; }
    __syncthreads();
    if (threadIdx.x == 0) {
        double       t_sle = 0.0, t_sva = 0.0;
        unsigned int t_cle = 0u,  t_cva = 0u;
        #pragma unroll
        for (int i = 0; i < 16; ++i) {
            t_sle += d_le[i]; t_sva += d_va[i]; t_cle += u_le[i]; t_cva += u_va[i];
        }
        const unsigned int nv = t_cva;
        const unsigned int k  = nv < MIN_KEPT ? nv : MIN_KEPT;
        if (MIN_KEPT >= nv) {                 // keep all valid
            out[0] = (float)(t_sva / (double)(nv > 0u ? nv : 1u));
            ws->flag = 0u;
        } else if (t_cle >= k) {              // threshold = 0.9 (normal path)
            out[0] = (float)(t_sle / (double)(t_cle > 0u ? t_cle : 1u));
            ws->flag = 0u;
        } else {
            unsigned int cum = t_cle;         // kth prob in (0.9, 1]
            int b = NBINS - 1;
            for (int i = 0; i < NBINS; ++i) {
                cum += ws->hist[i];
                if (cum >= k) { b = i; break; }
            }
            ws->threshold = 0.9f + (float)(b + 1) * (0.1f / (float)NBINS);
            ws->flag = 1u;
            out[0] = 0.0f;                    // overwritten by fallback
        }
    }
}

// Rare path: full recompute with histogram-derived (conservative) threshold;
// finalize fused via last-block arrival counter.
__global__ __launch_bounds__(256) void fallback_kernel(
        const float* __restrict__ pred, const int* __restrict__ tgt,
        Ws* __restrict__ ws, float* __restrict__ out, int npix_q) {
    if (ws->flag == 0u) return;   // normal case: exit immediately
    const float th = ws->threshold;
    const int stride = gridDim.x * blockDim.x;

    float        my_s = 0.0f;
    unsigned int my_c = 0u;
    for (int t = blockIdx.x * blockDim.x + threadIdx.x; t < npix_q; t += stride) {
        const int p0 = t << 2;
        const float* base = pred +
            (((size_t)(p0 >> PIX_SHIFT) * C) << PIX_SHIFT) + (p0 & PIX_MASK);
        const int4 li = *(const int4*)(tgt + p0);
        const int lab[4] = {li.x, li.y, li.z, li.w};
        float s[4] = {0,0,0,0}, l_lab[4] = {0,0,0,0};
        #pragma unroll
        for (int ci = 0; ci < C; ++ci) {
            const float4 v = *(const float4*)(base + ((size_t)ci << PIX_SHIFT));
            const float vv[4] = {v.x, v.y, v.z, v.w};
            #pragma unroll
            for (int j = 0; j < 4; ++j) {
                s[j] += __expf(vv[j]);
                if (lab[j] == ci) l_lab[j] = vv[j];
            }
        }
        #pragma unroll
        for (int j = 0; j < 4; ++j) {
            const float ls   = __logf(s[j]);
            const float nll  = ls - l_lab[j];
            const float prob = __expf(l_lab[j] - ls);
            if (lab[j] != IGNORE_LABEL && prob <= th) { my_c += 1u; my_s += nll; }
        }
    }
    __shared__ float        s_s[4];
    __shared__ unsigned int s_c[4];
    const int wid = threadIdx.x >> 6, lane = threadIdx.x & 63;
    const float        r_s = wave_reduce_f(my_s);
    const unsigned int r_c = wave_reduce_u(my_c);
    if (lane == 0) { s_s[wid] = r_s; s_c[wid] = r_c; }
    __syncthreads();
    if (threadIdx.x == 0) {
        const float        t_s = s_s[0] + s_s[1] + s_s[2] + s_s[3];
        const unsigned int t_c = s_c[0] + s_c[1] + s_c[2] + s_c[3];
        if (t_s != 0.0f) atomicAdd(&ws->sum_p3, (double)t_s);
        if (t_c)         atomicAdd(&ws->cnt_p3, t_c);
        __threadfence();
        const unsigned int prev = atomicAdd(&ws->done2, 1u);
        if (prev == gridDim.x - 1u) {          // last block finalizes
            const unsigned int cnt = ws->cnt_p3;
            out[0] = (float)(ws->sum_p3 / (double)(cnt > 0u ? cnt : 1u));
        }
    }
}

extern "C" void kernel_launch(void* const* d_in, const int* in_sizes, int n_in,
                              void* d_out, int out_size, void* d_ws, size_t ws_size,
                              hipStream_t stream) {
    const float* pred = (const float*)d_in[0];
    const int*   tgt  = (const int*)d_in[1];
    float*       out  = (float*)d_out;
    Ws*          ws   = (Ws*)d_ws;
    uint4*       partials = (uint4*)((char*)d_ws + sizeof(Ws));

    const int npix   = in_sizes[1];            // 2,097,152
    const int npix_q = npix >> 2;
    const int blocks = (npix + 2047) / 2048;   // 1024 blocks of 256 thr

    hipMemsetAsync(d_ws, 0, sizeof(Ws), stream);
    main_pass_kernel<<<blocks, 256, 0, stream>>>(pred, tgt, ws, partials, npix);
    reduce_finalize_kernel<<<1, 1024, 0, stream>>>(ws, partials, blocks, out);
    fallback_kernel<<<128, 256, 0, stream>>>(pred, tgt, ws, out, npix_q);
}

// Round 5
// 160.641 us; speedup vs baseline: 1.0070x; 1.0070x over previous
//
#include <hip/hip_runtime.h>
#include <hip/hip_bf16.h>
#include <math.h>

// CrossEntropy3d OHEM: predict (n=2, c=12, d=64, h=128, w=128) f32,
// target (2,64,128,128) int32. Class stride = d*h*w = 1<<20 floats (4 MB).
//
// R14 = R13 retry (R13 bench died with "container failed twice" -- no
// compile/pytest error, reads as infra flake; source re-audited: no
// early-return before barrier (1024*2048==npix), wave-uniform DMA dest,
// vmcnt(6) math correct incl. the 2 label loads, compiler models
// global_load_lds in its waitcnt pass (m97)).
//
// Experiment: counted-vmcnt double-buffered DMA pipeline (T3+T4 recipe).
// Evidence: R12 (DMA + __syncthreads drains) was neutral vs R11 -> peak MLP
// is fine, but in-flight bytes sawtooth 12KB->0 at every barrier because
// __syncthreads == s_waitcnt vmcnt(0)+lgkmcnt(0)+s_barrier. This round
// keeps 6 DMAs/wave permanently in flight: issue STAGE(p+1), then
// s_waitcnt vmcnt(6) (phase p landed, p+1 still flying), raw s_barrier,
// compute phase p, lgkmcnt(0)+raw barrier (buffer reuse). 4 phases x 3
// classes, 2 x 24KB LDS buffers, 3 blocks/CU.
// If neutral: sustained MLP is not the lever; the ~2 TB/s plateau is
// same-L2-set serialization of 12 x 4MB-aliased class streams (below
// source control) -> revert to R11 and declare the floor.
// R10 lesson kept: no per-block device fences/atomics in the hot path.
// Fixed harness overhead in timed window: ws poison ~59us + d_in restore
// ~33us => ~95us floor.

#define IGNORE_LABEL 255
#define MIN_KEPT 10000u

constexpr int   C         = 12;
constexpr int   PIX_SHIFT = 20;              // d*h*w = 1<<20
constexpr int   PIX_MASK  = (1 << PIX_SHIFT) - 1;
constexpr int   NBINS     = 2048;            // histogram over (0.9, 1.0]
constexpr float BIN_SCALE = (float)NBINS / 0.1f;

struct Ws {
    double       sum_p3;     // fallback sum (atomics; rare path only)
    unsigned int cnt_p3;
    unsigned int flag;       // 1 => fallback must run
    float        threshold;  // fallback threshold
    unsigned int done;       // main-pass arrival counter (unused here)
    unsigned int done2;      // fallback arrival counter
    unsigned int pad[9];     // pad to 64 B
    unsigned int hist[NBINS];
};
// uint4 per main block (sle, sva as float bits; cle, cva) right after Ws.

__device__ inline float wave_reduce_f(float v) {
    #pragma unroll
    for (int o = 32; o > 0; o >>= 1) v += __shfl_down(v, o, 64);
    return v;
}
__device__ inline unsigned int wave_reduce_u(unsigned int v) {
    #pragma unroll
    for (int o = 32; o > 0; o >>= 1) v += __shfl_down(v, o, 64);
    return v;
}
__device__ inline double wave_reduce_d(double v) {
    #pragma unroll
    for (int o = 32; o > 0; o >>= 1) v += __shfl_down(v, o, 64);
    return v;
}

// 16B-per-lane global->LDS DMA. LDS dest = base + lane*16 (wave-uniform
// base); global src is per-lane. Size must be a literal (guide §5).
__device__ inline void stage16(const float* g, float* l) {
    __builtin_amdgcn_global_load_lds(
        (const __attribute__((address_space(1))) void*)g,
        (__attribute__((address_space(3))) void*)l,
        16, 0, 0);
}

__global__ __launch_bounds__(256, 3) void main_pass_kernel(
        const float* __restrict__ pred, const int* __restrict__ tgt,
        Ws* __restrict__ ws, uint4* __restrict__ partials, int npix) {
    __shared__ float smem[2 * 3 * 2048];      // 48 KB: 2 bufs x 3 classes

    const int blk   = blockIdx.x;
    const int t     = threadIdx.x;
    const int wave  = t >> 6, lane = t & 63;
    const int bpix0 = blk << 11;              // 2048 px per block
    if (bpix0 >= npix) return;                // never true at this shape

    const size_t sbase = (((size_t)(bpix0 >> PIX_SHIFT) * C) << PIX_SHIFT)
                       + (size_t)(bpix0 & PIX_MASK);

    // labels first in issue order (counted-vmcnt math accounts for them)
    const int4 la = *(const int4*)(tgt + bpix0 + (t << 2));
    const int4 lb = *(const int4*)(tgt + bpix0 + 1024 + (t << 2));
    const int lab[8] = {la.x, la.y, la.z, la.w, lb.x, lb.y, lb.z, lb.w};

    float E[8]  = {0,0,0,0,0,0,0,0};
    float ll[8] = {0,0,0,0,0,0,0,0};

    // per-wave staging source: wave w covers px [w*512, w*512+512)/class
    const float* gw = pred + sbase + (wave << 9) + (lane << 2);

    // 6 DMAs/wave per phase (3 classes x 2x 1KB), wave-uniform LDS dest
#define STAGE(ph, buf) do {                                                  \
        _Pragma("unroll")                                                    \
        for (int ci = 0; ci < 3; ++ci) {                                     \
            const int c_ = (ph) * 3 + ci;                                    \
            const float* g0_ = gw + ((size_t)c_ << PIX_SHIFT);               \
            float* l0_ = smem + (buf) * 6144 + ci * 2048 + (wave << 9);      \
            stage16(g0_,       l0_);                                         \
            stage16(g0_ + 256, l0_ + 256);                                   \
        }                                                                    \
        asm volatile("" ::: "memory"); /* pin DMA issue order */             \
    } while (0)

#define COMPUTE(ph, buf) do {                                                \
        _Pragma("unroll")                                                    \
        for (int ci = 0; ci < 3; ++ci) {                                     \
            const int c_ = (ph) * 3 + ci;                                    \
            const float4 v0_ = *(const float4*)(smem + (buf) * 6144 +        \
                                                ci * 2048 + (t << 2));       \
            const float4 v1_ = *(const float4*)(smem + (buf) * 6144 +        \
                                                ci * 2048 + 1024 + (t << 2));\
            const float vv_[8] = {v0_.x, v0_.y, v0_.z, v0_.w,                \
                                  v1_.x, v1_.y, v1_.z, v1_.w};               \
            _Pragma("unroll")                                                \
            for (int j = 0; j < 8; ++j) {                                    \
                E[j] += __expf(vv_[j]);                                      \
                if (lab[j] == c_) ll[j] = vv_[j];                            \
            }                                                                \
        }                                                                    \
    } while (0)

#define WAITV6()  asm volatile("s_waitcnt vmcnt(6)"  ::: "memory")
#define WAITV0()  asm volatile("s_waitcnt vmcnt(0)"  ::: "memory")
#define WAITL0()  asm volatile("s_waitcnt lgkmcnt(0)" ::: "memory")

    STAGE(0, 0);                              // prologue

    // iter 0: p0 in buf0, prefetch p1 -> buf1
    STAGE(1, 1);
    WAITV6();  __builtin_amdgcn_s_barrier();  // p0 landed (6 newest = p1 fly)
    COMPUTE(0, 0);
    WAITL0();  __builtin_amdgcn_s_barrier();  // buf0 free for reuse

    // iter 1: p1 in buf1, prefetch p2 -> buf0
    STAGE(2, 0);
    WAITV6();  __builtin_amdgcn_s_barrier();
    COMPUTE(1, 1);
    WAITL0();  __builtin_amdgcn_s_barrier();

    // iter 2: p2 in buf0, prefetch p3 -> buf1
    STAGE(3, 1);
    WAITV6();  __builtin_amdgcn_s_barrier();
    COMPUTE(2, 0);
    WAITL0();  __builtin_amdgcn_s_barrier();

    // tail: p3 in buf1, nothing left to prefetch
    WAITV0();  __builtin_amdgcn_s_barrier();
    COMPUTE(3, 1);

#undef STAGE
#undef COMPUTE
#undef WAITV6
#undef WAITV0
#undef WAITL0

    float        my_sle = 0.0f, my_sva = 0.0f;
    unsigned int my_cle = 0u,   my_cva = 0u;
    #pragma unroll
    for (int j = 0; j < 8; ++j) {
        const float ls   = __logf(E[j]);
        const float nll  = ls - ll[j];
        const float prob = __expf(ll[j] - ls);
        if (lab[j] != IGNORE_LABEL) {
            my_cva += 1u;
            my_sva += nll;
            if (prob <= 0.9f) {
                my_cle += 1u;
                my_sle += nll;
            } else {
                int b = (int)((prob - 0.9f) * BIN_SCALE);
                b = b < 0 ? 0 : (b >= NBINS - 1 ? NBINS - 1 : b);
                atomicAdd(&ws->hist[b], 1u);   // rare
            }
        }
    }

    __shared__ float        s_le[4], s_va[4];
    __shared__ unsigned int s_cle[4], s_cva[4];
    const float        r_le = wave_reduce_f(my_sle);
    const float        r_va = wave_reduce_f(my_sva);
    const unsigned int r_cl = wave_reduce_u(my_cle);
    const unsigned int r_cv = wave_reduce_u(my_cva);
    if (lane == 0) { s_le[wave] = r_le; s_va[wave] = r_va; s_cle[wave] = r_cl; s_cva[wave] = r_cv; }
    __syncthreads();
    if (t == 0) {
        uint4 p;
        p.x = __float_as_uint(s_le[0] + s_le[1] + s_le[2] + s_le[3]);
        p.y = __float_as_uint(s_va[0] + s_va[1] + s_va[2] + s_va[3]);
        p.z = s_cle[0] + s_cle[1] + s_cle[2] + s_cle[3];
        p.w = s_cva[0] + s_cva[1] + s_cva[2] + s_cva[3];
        partials[blk] = p;   // fire-and-forget, distinct lines
    }
}

__global__ __launch_bounds__(1024) void reduce_finalize_kernel(
        Ws* __restrict__ ws, const uint4* __restrict__ partials,
        int nblocks, float* __restrict__ out) {
    double       sle = 0.0, sva = 0.0;
    unsigned int cle = 0u,  cva = 0u;
    for (int i = threadIdx.x; i < nblocks; i += 1024) {
        const uint4 p = partials[i];
        sle += (double)__uint_as_float(p.x);
        sva += (double)__uint_as_float(p.y);
        cle += p.z;
        cva += p.w;
    }
    __shared__ double       d_le[16], d_va[16];
    __shared__ unsigned int u_le[16], u_va[16];
    const int wid = threadIdx.x >> 6, lane = threadIdx.x & 63;
    const double       r_sle = wave_reduce_d(sle);
    const double       r_sva = wave_reduce_d(sva);
    const unsigned int r_cle = wave_reduce_u(cle);
    const unsigned int r_cva = wave_reduce_u(cva);
    if (lane == 0) { d_le[wid] = r_sle; d_va[wid] = r_sva; u_le[wid] = r_cle; u_va[wid] = r_cva; }
    __syncthreads();
    if (threadIdx.x == 0) {
        double       t_sle = 0.0, t_sva = 0.0;
        unsigned int t_cle = 0u,  t_cva = 0u;
        #pragma unroll
        for (int i = 0; i < 16; ++i) {
            t_sle += d_le[i]; t_sva += d_va[i]; t_cle += u_le[i]; t_cva += u_va[i];
        }
        const unsigned int nv = t_cva;
        const unsigned int k  = nv < MIN_KEPT ? nv : MIN_KEPT;
        if (MIN_KEPT >= nv) {                 // keep all valid
            out[0] = (float)(t_sva / (double)(nv > 0u ? nv : 1u));
            ws->flag = 0u;
        } else if (t_cle >= k) {              // threshold = 0.9 (normal path)
            out[0] = (float)(t_sle / (double)(t_cle > 0u ? t_cle : 1u));
            ws->flag = 0u;
        } else {
            unsigned int cum = t_cle;         // kth prob in (0.9, 1]
            int b = NBINS - 1;
            for (int i = 0; i < NBINS; ++i) {
                cum += ws->hist[i];
                if (cum >= k) { b = i; break; }
            }
            ws->threshold = 0.9f + (float)(b + 1) * (0.1f / (float)NBINS);
            ws->flag = 1u;
            out[0] = 0.0f;                    // overwritten by fallback
        }
    }
}

// Rare path: full recompute with histogram-derived (conservative) threshold;
// finalize fused via last-block arrival counter.
__global__ __launch_bounds__(256) void fallback_kernel(
        const float* __restrict__ pred, const int* __restrict__ tgt,
        Ws* __restrict__ ws, float* __restrict__ out, int npix_q) {
    if (ws->flag == 0u) return;   // normal case: exit immediately
    const float th = ws->threshold;
    const int stride = gridDim.x * blockDim.x;

    float        my_s = 0.0f;
    unsigned int my_c = 0u;
    for (int t = blockIdx.x * blockDim.x + threadIdx.x; t < npix_q; t += stride) {
        const int p0 = t << 2;
        const float* base = pred +
            (((size_t)(p0 >> PIX_SHIFT) * C) << PIX_SHIFT) + (p0 & PIX_MASK);
        const int4 li = *(const int4*)(tgt + p0);
        const int lab[4] = {li.x, li.y, li.z, li.w};
        float s[4] = {0,0,0,0}, l_lab[4] = {0,0,0,0};
        #pragma unroll
        for (int ci = 0; ci < C; ++ci) {
            const float4 v = *(const float4*)(base + ((size_t)ci << PIX_SHIFT));
            const float vv[4] = {v.x, v.y, v.z, v.w};
            #pragma unroll
            for (int j = 0; j < 4; ++j) {
                s[j] += __expf(vv[j]);
                if (lab[j] == ci) l_lab[j] = vv[j];
            }
        }
        #pragma unroll
        for (int j = 0; j < 4; ++j) {
            const float ls   = __logf(s[j]);
            const float nll  = ls - l_lab[j];
            const float prob = __expf(l_lab[j] - ls);
            if (lab[j] != IGNORE_LABEL && prob <= th) { my_c += 1u; my_s += nll; }
        }
    }
    __shared__ float        s_s[4];
    __shared__ unsigned int s_c[4];
    const int wid = threadIdx.x >> 6, lane = threadIdx.x & 63;
    const float        r_s = wave_reduce_f(my_s);
    const unsigned int r_c = wave_reduce_u(my_c);
    if (lane == 0) { s_s[wid] = r_s; s_c[wid] = r_c; }
    __syncthreads();
    if (threadIdx.x == 0) {
        const float        t_s = s_s[0] + s_s[1] + s_s[2] + s_s[3];
        const unsigned int t_c = s_c[0] + s_c[1] + s_c[2] + s_c[3];
        if (t_s != 0.0f) atomicAdd(&ws->sum_p3, (double)t_s);
        if (t_c)         atomicAdd(&ws->cnt_p3, t_c);
        __threadfence();
        const unsigned int prev = atomicAdd(&ws->done2, 1u);
        if (prev == gridDim.x - 1u) {          // last block finalizes
            const unsigned int cnt = ws->cnt_p3;
            out[0] = (float)(ws->sum_p3 / (double)(cnt > 0u ? cnt : 1u));
        }
    }
}

extern "C" void kernel_launch(void* const* d_in, const int* in_sizes, int n_in,
                              void* d_out, int out_size, void* d_ws, size_t ws_size,
                              hipStream_t stream) {
    const float* pred = (const float*)d_in[0];
    const int*   tgt  = (const int*)d_in[1];
    float*       out  = (float*)d_out;
    Ws*          ws   = (Ws*)d_ws;
    uint4*       partials = (uint4*)((char*)d_ws + sizeof(Ws));

    const int npix   = in_sizes[1];            // 2,097,152
    const int npix_q = npix >> 2;
    const int blocks = (npix + 2047) / 2048;   // 1024 blocks of 256 thr

    hipMemsetAsync(d_ws, 0, sizeof(Ws), stream);
    main_pass_kernel<<<blocks, 256, 0, stream>>>(pred, tgt, ws, partials, npix);
    reduce_finalize_kernel<<<1, 1024, 0, stream>>>(ws, partials, blocks, out);
    fallback_kernel<<<128, 256, 0, stream>>>(pred, tgt, ws, out, npix_q);
}

// Round 6
// 158.421 us; speedup vs baseline: 1.0211x; 1.0140x over previous
//
#include <hip/hip_runtime.h>
#include <hip/hip_bf16.h>
#include <math.h>

// CrossEntropy3d OHEM: predict (n=2, c=12, d=64, h=128, w=128) f32,
// target (2,64,128,128) int32. Class stride = d*h*w = 1<<20 floats (4 MB).
//
// R15: FINAL — revert to the best harness-verified kernel (R11, 156.7us).
//
// Complete experiment ledger for main_pass (the only addressable piece):
//   R5  2x waves (TLP)                         -> neutral
//   R6  nt cache-bypass                        -> worse; LLC replay same dur
//   R7  VGPR->LDS staging                      -> neutral
//   R8  wide live loads (peak MLP)             -> neutral
//   R9  per-class stream dwell                 -> neutral
//   R10 fused last-block reduce                -> -45us (1024 device fences +
//        same-line atomics serialize at fabric; dispatch boundary IS the
//        cheap batched release/acquire for producer->consumer handoff)
//   R12 global_load_lds DMA, drain barriers    -> neutral
//   R14 DMA + counted vmcnt(6) raw barriers    -> neutral (sustained MLP)
// Every mechanically distinct load structure converges at ~2 TB/s effective
// read for this kernel while plain fills run 6.7 TB/s on the same chip.
// Conclusion: the 12 class streams at exactly 4MB stride alias in the
// L2/fabric sets; the serialization is below HIP source control.
//
// Floor arithmetic: ws poison ~59.5us (84-86% HBM peak, itself roofline) +
// d_in restore ~33us + main_pass ~52us (104 MB @ pattern-limited ~2 TB/s) +
// memset/reduce/fallback + 4 launch gaps ~10us  =>  ~155us. Measured: 156.7.

#define IGNORE_LABEL 255
#define MIN_KEPT 10000u

constexpr int   C         = 12;
constexpr int   PIX_SHIFT = 20;              // d*h*w = 1<<20
constexpr int   PIX_MASK  = (1 << PIX_SHIFT) - 1;
constexpr int   NBINS     = 2048;            // histogram over (0.9, 1.0]
constexpr float BIN_SCALE = (float)NBINS / 0.1f;

struct Ws {
    double       sum_p3;     // fallback sum (atomics; rare path only)
    unsigned int cnt_p3;
    unsigned int flag;       // 1 => fallback must run
    float        threshold;  // fallback threshold
    unsigned int done;       // main-pass arrival counter (unused here)
    unsigned int done2;      // fallback arrival counter
    unsigned int pad[9];     // pad to 64 B
    unsigned int hist[NBINS];
};
// uint4 per main block (sle, sva as float bits; cle, cva) right after Ws.

__device__ inline float wave_reduce_f(float v) {
    #pragma unroll
    for (int o = 32; o > 0; o >>= 1) v += __shfl_down(v, o, 64);
    return v;
}
__device__ inline unsigned int wave_reduce_u(unsigned int v) {
    #pragma unroll
    for (int o = 32; o > 0; o >>= 1) v += __shfl_down(v, o, 64);
    return v;
}
__device__ inline double wave_reduce_d(double v) {
    #pragma unroll
    for (int o = 32; o > 0; o >>= 1) v += __shfl_down(v, o, 64);
    return v;
}

__global__ __launch_bounds__(256, 4) void main_pass_kernel(
        const float* __restrict__ pred, const int* __restrict__ tgt,
        Ws* __restrict__ ws, uint4* __restrict__ partials, int npix) {
    const int tid = blockIdx.x * blockDim.x + threadIdx.x;

    float        my_sle = 0.0f, my_sva = 0.0f;
    unsigned int my_cle = 0u,   my_cva = 0u;

    const int p0 = tid << 3;                  // 8 consecutive pixels
    if (p0 < npix) {
        const float* base = pred +
            (((size_t)(p0 >> PIX_SHIFT) * C) << PIX_SHIFT) + (p0 & PIX_MASK);
        const int4 la = *(const int4*)(tgt + p0);
        const int4 lb = *(const int4*)(tgt + p0 + 4);
        const int lab[8] = {la.x, la.y, la.z, la.w, lb.x, lb.y, lb.z, lb.w};

        // loop-carried per-pixel state: exp-sum + label logit (cannot be sunk)
        float E[8]  = {0,0,0,0,0,0,0,0};
        float ll[8] = {0,0,0,0,0,0,0,0};
        #pragma unroll
        for (int ci = 0; ci < C; ++ci) {
            const float* csrc = base + ((size_t)ci << PIX_SHIFT);
            const float4 v0 = *(const float4*)(csrc);
            const float4 v1 = *(const float4*)(csrc + 4);
            const float vv[8] = {v0.x, v0.y, v0.z, v0.w, v1.x, v1.y, v1.z, v1.w};
            #pragma unroll
            for (int j = 0; j < 8; ++j) {
                E[j] += __expf(vv[j]);
                if (lab[j] == ci) ll[j] = vv[j];
            }
        }
        #pragma unroll
        for (int j = 0; j < 8; ++j) {
            const float ls   = __logf(E[j]);
            const float nll  = ls - ll[j];
            const float prob = __expf(ll[j] - ls);
            if (lab[j] != IGNORE_LABEL) {
                my_cva += 1u;
                my_sva += nll;
                if (prob <= 0.9f) {
                    my_cle += 1u;
                    my_sle += nll;
                } else {
                    int b = (int)((prob - 0.9f) * BIN_SCALE);
                    b = b < 0 ? 0 : (b >= NBINS - 1 ? NBINS - 1 : b);
                    atomicAdd(&ws->hist[b], 1u);   // rare
                }
            }
        }
    }

    __shared__ float        s_le[4], s_va[4];
    __shared__ unsigned int s_cle[4], s_cva[4];
    const int wid = threadIdx.x >> 6, lane = threadIdx.x & 63;
    const float        r_le = wave_reduce_f(my_sle);
    const float        r_va = wave_reduce_f(my_sva);
    const unsigned int r_cl = wave_reduce_u(my_cle);
    const unsigned int r_cv = wave_reduce_u(my_cva);
    if (lane == 0) { s_le[wid] = r_le; s_va[wid] = r_va; s_cle[wid] = r_cl; s_cva[wid] = r_cv; }
    __syncthreads();
    if (threadIdx.x == 0) {
        uint4 p;
        p.x = __float_as_uint(s_le[0] + s_le[1] + s_le[2] + s_le[3]);
        p.y = __float_as_uint(s_va[0] + s_va[1] + s_va[2] + s_va[3]);
        p.z = s_cle[0] + s_cle[1] + s_cle[2] + s_cle[3];
        p.w = s_cva[0] + s_cva[1] + s_cva[2] + s_cva[3];
        partials[blockIdx.x] = p;   // fire-and-forget, distinct lines
    }
}

__global__ __launch_bounds__(1024) void reduce_finalize_kernel(
        Ws* __restrict__ ws, const uint4* __restrict__ partials,
        int nblocks, float* __restrict__ out) {
    double       sle = 0.0, sva = 0.0;
    unsigned int cle = 0u,  cva = 0u;
    for (int i = threadIdx.x; i < nblocks; i += 1024) {
        const uint4 p = partials[i];
        sle += (double)__uint_as_float(p.x);
        sva += (double)__uint_as_float(p.y);
        cle += p.z;
        cva += p.w;
    }
    __shared__ double       d_le[16], d_va[16];
    __shared__ unsigned int u_le[16], u_va[16];
    const int wid = threadIdx.x >> 6, lane = threadIdx.x & 63;
    const double       r_sle = wave_reduce_d(sle);
    const double       r_sva = wave_reduce_d(sva);
    const unsigned int r_cle = wave_reduce_u(cle);
    const unsigned int r_cva = wave_reduce_u(cva);
    if (lane == 0) { d_le[wid] = r_sle; d_va[wid] = r_sva; u_le[wid] = r_cle; u_va[wid] = r_cva; }
    __syncthreads();
    if (threadIdx.x == 0) {
        double       t_sle = 0.0, t_sva = 0.0;
        unsigned int t_cle = 0u,  t_cva = 0u;
        #pragma unroll
        for (int i = 0; i < 16; ++i) {
            t_sle += d_le[i]; t_sva += d_va[i]; t_cle += u_le[i]; t_cva += u_va[i];
        }
        const unsigned int nv = t_cva;
        const unsigned int k  = nv < MIN_KEPT ? nv : MIN_KEPT;
        if (MIN_KEPT >= nv) {                 // keep all valid
            out[0] = (float)(t_sva / (double)(nv > 0u ? nv : 1u));
            ws->flag = 0u;
        } else if (t_cle >= k) {              // threshold = 0.9 (normal path)
            out[0] = (float)(t_sle / (double)(t_cle > 0u ? t_cle : 1u));
            ws->flag = 0u;
        } else {
            unsigned int cum = t_cle;         // kth prob in (0.9, 1]
            int b = NBINS - 1;
            for (int i = 0; i < NBINS; ++i) {
                cum += ws->hist[i];
                if (cum >= k) { b = i; break; }
            }
            ws->threshold = 0.9f + (float)(b + 1) * (0.1f / (float)NBINS);
            ws->flag = 1u;
            out[0] = 0.0f;                    // overwritten by fallback
        }
    }
}

// Rare path: full recompute with histogram-derived (conservative) threshold;
// finalize fused via last-block arrival counter.
__global__ __launch_bounds__(256) void fallback_kernel(
        const float* __restrict__ pred, const int* __restrict__ tgt,
        Ws* __restrict__ ws, float* __restrict__ out, int npix_q) {
    if (ws->flag == 0u) return;   // normal case: exit immediately
    const float th = ws->threshold;
    const int stride = gridDim.x * blockDim.x;

    float        my_s = 0.0f;
    unsigned int my_c = 0u;
    for (int t = blockIdx.x * blockDim.x + threadIdx.x; t < npix_q; t += stride) {
        const int p0 = t << 2;
        const float* base = pred +
            (((size_t)(p0 >> PIX_SHIFT) * C) << PIX_SHIFT) + (p0 & PIX_MASK);
        const int4 li = *(const int4*)(tgt + p0);
        const int lab[4] = {li.x, li.y, li.z, li.w};
        float s[4] = {0,0,0,0}, l_lab[4] = {0,0,0,0};
        #pragma unroll
        for (int ci = 0; ci < C; ++ci) {
            const float4 v = *(const float4*)(base + ((size_t)ci << PIX_SHIFT));
            const float vv[4] = {v.x, v.y, v.z, v.w};
            #pragma unroll
            for (int j = 0; j < 4; ++j) {
                s[j] += __expf(vv[j]);
                if (lab[j] == ci) l_lab[j] = vv[j];
            }
        }
        #pragma unroll
        for (int j = 0; j < 4; ++j) {
            const float ls   = __logf(s[j]);
            const float nll  = ls - l_lab[j];
            const float prob = __expf(l_lab[j] - ls);
            if (lab[j] != IGNORE_LABEL && prob <= th) { my_c += 1u; my_s += nll; }
        }
    }
    __shared__ float        s_s[4];
    __shared__ unsigned int s_c[4];
    const int wid = threadIdx.x >> 6, lane = threadIdx.x & 63;
    const float        r_s = wave_reduce_f(my_s);
    const unsigned int r_c = wave_reduce_u(my_c);
    if (lane == 0) { s_s[wid] = r_s; s_c[wid] = r_c; }
    __syncthreads();
    if (threadIdx.x == 0) {
        const float        t_s = s_s[0] + s_s[1] + s_s[2] + s_s[3];
        const unsigned int t_c = s_c[0] + s_c[1] + s_c[2] + s_c[3];
        if (t_s != 0.0f) atomicAdd(&ws->sum_p3, (double)t_s);
        if (t_c)         atomicAdd(&ws->cnt_p3, t_c);
        __threadfence();
        const unsigned int prev = atomicAdd(&ws->done2, 1u);
        if (prev == gridDim.x - 1u) {          // last block finalizes
            const unsigned int cnt = ws->cnt_p3;
            out[0] = (float)(ws->sum_p3 / (double)(cnt > 0u ? cnt : 1u));
        }
    }
}

extern "C" void kernel_launch(void* const* d_in, const int* in_sizes, int n_in,
                              void* d_out, int out_size, void* d_ws, size_t ws_size,
                              hipStream_t stream) {
    const float* pred = (const float*)d_in[0];
    const int*   tgt  = (const int*)d_in[1];
    float*       out  = (float*)d_out;
    Ws*          ws   = (Ws*)d_ws;
    uint4*       partials = (uint4*)((char*)d_ws + sizeof(Ws));

    const int npix   = in_sizes[1];            // 2,097,152
    const int npix_q = npix >> 2;
    const int blocks = (npix / 8 + 255) / 256; // 1024 blocks of 256 thr

    hipMemsetAsync(d_ws, 0, sizeof(Ws), stream);
    main_pass_kernel<<<blocks, 256, 0, stream>>>(pred, tgt, ws, partials, npix);
    reduce_finalize_kernel<<<1, 1024, 0, stream>>>(ws, partials, blocks, out);
    fallback_kernel<<<128, 256, 0, stream>>>(pred, tgt, ws, out, npix_q);
}